// Round 8
// baseline (30.317 us; speedup 1.0000x reference)
//
#include <hip/hip_runtime.h>

// RoI max-pool, channel-last, XCD-localized by image.
// features [4,256,38,38] f32, rois [512,5] f32, out [512,256,7,7] f32.
//
// ws: featT [4][1444][256] f32 | perm[512] int | cnt[4] int | off[4] int
//
// Kernel 1: transpose features -> featT; block (0,0) also buckets ROI
//           indices by image into perm (order within bucket irrelevant).
// Kernel 2: flat 4096-block grid. xcd = bid&7 (round-robin dispatch
//           heuristic), image = xcd>>1 -> each XCD reads only its image's
//           1.48 MB slice => L2-resident. Unit = (roi, cg, p-half); one
//           p-row per wave, compile-time row width via switch(ww).

#define NROIS 512
#define CCH   256
#define FH    38
#define FW    38
#define HW    (FH * FW)          // 1444
#define SCALE 0.0625f
#define NEGF  (-3.402823466e+38f)

#define FEATT_BYTES ((size_t)4 * HW * CCH * sizeof(float))   // 5,914,624

// ---------------- Kernel 1: transpose + ROI bucketing ----------------
__global__ __launch_bounds__(256) void transpose_bucket_kernel(
    const float* __restrict__ src, const float* __restrict__ rois,
    float* __restrict__ dst, int* __restrict__ perm,
    int* __restrict__ cntG, int* __restrict__ offG)
{
    __shared__ float tile[4][257];
    __shared__ int cntS[4], baseS[4];

    const int b  = blockIdx.y;
    const int s0 = blockIdx.x * 4;
    const int t  = threadIdx.x;                 // = channel

    const float4 v = *(const float4*)(src + ((size_t)(b * CCH + t)) * HW + s0);
    tile[0][t] = v.x; tile[1][t] = v.y; tile[2][t] = v.z; tile[3][t] = v.w;
    __syncthreads();

    const int s = t >> 6;                       // 0..3
    const int m = t & 63;
    float* drow = dst + ((size_t)b * HW + s0 + s) * CCH;
    #pragma unroll
    for (int k = 0; k < 4; ++k)
        drow[m + 64 * k] = tile[s][m + 64 * k];

    // ---- bucketing (one block only) ----
    if (blockIdx.x == 0 && blockIdx.y == 0) {
        if (t < 4) cntS[t] = 0;
        __syncthreads();
        const int b0 = (int)rois[t * 5];
        const int p0 = atomicAdd(&cntS[b0], 1);
        const int b1 = (int)rois[(t + 256) * 5];
        const int p1 = atomicAdd(&cntS[b1], 1);
        __syncthreads();
        if (t == 0) {
            int acc = 0;
            #pragma unroll
            for (int i = 0; i < 4; ++i) {
                baseS[i] = acc;
                cntG[i] = cntS[i];
                offG[i] = acc;
                acc += cntS[i];
            }
        }
        __syncthreads();
        perm[baseS[b0] + p0] = t;
        perm[baseS[b1] + p1] = t + 256;
    }
}

// ---------------- Kernel 2: pooling ----------------
template <int WW>
__device__ __forceinline__ void pool_one(
    const float* __restrict__ rb, int h, float (&acc)[7])
{
    for (int y = 0; y < h; ++y) {
        float v[WW];
        #pragma unroll
        for (int j = 0; j < WW; ++j) v[j] = rb[j * CCH];
        #pragma unroll
        for (int q = 0; q < 7; ++q) {
            const int xs = (q * WW) / 7;
            const int xe = ((q + 1) * WW + 6) / 7;
            #pragma unroll
            for (int j = xs; j < xe; ++j)
                acc[q] = fmaxf(acc[q], v[j]);
        }
        rb += (size_t)FW * CCH;
    }
}

template <int NB>
__device__ __forceinline__ void write_out(
    float* __restrict__ outb, const float (*__restrict__ sm)[65], int tid)
{
    #pragma unroll
    for (int flat = 0; flat < 64 * NB; flat += 256) {
        const int f = flat + tid;
        if (f < 64 * NB) {
            const int c = f / NB;               // compile-time magic div
            const int l = f - c * NB;
            outb[c * 49 + l] = sm[l][c];
        }
    }
}

__global__ __launch_bounds__(256) void roipool_kernel(
    const float* __restrict__ featT,
    const float* __restrict__ rois,
    const int* __restrict__ perm,
    const int* __restrict__ cntG,
    const int* __restrict__ offG,
    float* __restrict__ out)
{
    __shared__ float smem[28][65];

    const int bid  = blockIdx.x;
    const int xcd  = bid & 7;
    const int slot = bid >> 3;                 // 0..511
    const int img  = xcd >> 1;                 // 2 XCDs per image
    const int half = xcd & 1;
    const int tid  = threadIdx.x;
    const int wv   = __builtin_amdgcn_readfirstlane(tid >> 6);
    const int lane = tid & 63;

    const int cnt = cntG[img];
    const int off = offG[img];
    const int nunits = cnt * 8;                // (roi, cg, ph) units

    for (int g = slot * 2 + half; g < nunits; g += 1024) {
        const int r  = perm[off + (g >> 3)];   // ROI index
        const int u  = g & 7;
        const int cg = u & 3;                  // g&1 == half == cg&1
        const int ph = u >> 2;

        // ROI decode (uniform per block)
        const float* rr = rois + r * 5;
        const int bb = (int)rr[0];
        int x1 = (int)(rr[1] * SCALE);
        int y1 = (int)(rr[2] * SCALE);
        int x2 = (int)(rr[3] * SCALE);
        int y2 = (int)(rr[4] * SCALE);
        x1 = min(max(x1, 0), FW - 1);
        y1 = min(max(y1, 0), FH - 1);
        x2 = min(max(x2, 0), FW - 1);
        y2 = min(max(y2, 0), FH - 1);
        const int hh = y2 - y1 + 1;
        const int ww = x2 - x1 + 1;            // 1..38, block-uniform

        const int p = 4 * ph + wv;             // one p-row per wave
        if (p < 7) {
            const int ys = y1 + (p * hh) / 7;
            const int h  = (y1 + ((p + 1) * hh + 6) / 7) - ys;

            const float* rb0 = featT + (size_t)bb * HW * CCH + cg * 64 + lane
                             + (size_t)(ys * FW + x1) * CCH;

            float acc[7];
            #pragma unroll
            for (int q = 0; q < 7; ++q) acc[q] = NEGF;

            switch (ww) {
                case  1: pool_one< 1>(rb0, h, acc); break;
                case  2: pool_one< 2>(rb0, h, acc); break;
                case  3: pool_one< 3>(rb0, h, acc); break;
                case  4: pool_one< 4>(rb0, h, acc); break;
                case  5: pool_one< 5>(rb0, h, acc); break;
                case  6: pool_one< 6>(rb0, h, acc); break;
                case  7: pool_one< 7>(rb0, h, acc); break;
                case  8: pool_one< 8>(rb0, h, acc); break;
                case  9: pool_one< 9>(rb0, h, acc); break;
                case 10: pool_one<10>(rb0, h, acc); break;
                case 11: pool_one<11>(rb0, h, acc); break;
                case 12: pool_one<12>(rb0, h, acc); break;
                case 13: pool_one<13>(rb0, h, acc); break;
                case 14: pool_one<14>(rb0, h, acc); break;
                case 15: pool_one<15>(rb0, h, acc); break;
                case 16: pool_one<16>(rb0, h, acc); break;
                case 17: pool_one<17>(rb0, h, acc); break;
                case 18: pool_one<18>(rb0, h, acc); break;
                case 19: pool_one<19>(rb0, h, acc); break;
                case 20: pool_one<20>(rb0, h, acc); break;
                case 21: pool_one<21>(rb0, h, acc); break;
                case 22: pool_one<22>(rb0, h, acc); break;
                case 23: pool_one<23>(rb0, h, acc); break;
                case 24: pool_one<24>(rb0, h, acc); break;
                case 25: pool_one<25>(rb0, h, acc); break;
                case 26: pool_one<26>(rb0, h, acc); break;
                case 27: pool_one<27>(rb0, h, acc); break;
                case 28: pool_one<28>(rb0, h, acc); break;
                case 29: pool_one<29>(rb0, h, acc); break;
                case 30: pool_one<30>(rb0, h, acc); break;
                case 31: pool_one<31>(rb0, h, acc); break;
                case 32: pool_one<32>(rb0, h, acc); break;
                case 33: pool_one<33>(rb0, h, acc); break;
                case 34: pool_one<34>(rb0, h, acc); break;
                case 35: pool_one<35>(rb0, h, acc); break;
                case 36: pool_one<36>(rb0, h, acc); break;
                case 37: pool_one<37>(rb0, h, acc); break;
                default: pool_one<38>(rb0, h, acc); break;
            }

            #pragma unroll
            for (int q = 0; q < 7; ++q)
                smem[wv * 7 + q][lane] = acc[q];
        }
        __syncthreads();

        float* outb = out + (size_t)r * (CCH * 49) + cg * (64 * 49) + ph * 28;
        if (ph == 0) write_out<28>(outb, smem, tid);
        else         write_out<21>(outb, smem, tid);
        __syncthreads();   // smem reused next iteration
    }
}

// ---------------- Fallback (ws too small) ----------------
__global__ __launch_bounds__(256) void roipool_fallback(
    const float* __restrict__ feat,
    const float* __restrict__ rois,
    float* __restrict__ out)
{
    int idx = blockIdx.x * blockDim.x + threadIdx.x;
    int q = idx % 7;
    int t = idx / 7;
    int p = t % 7;
    t /= 7;
    int c = t % CCH;
    int n = t / CCH;

    const float* r = rois + n * 5;
    int b  = (int)r[0];
    int x1 = (int)(r[1] * SCALE);
    int y1 = (int)(r[2] * SCALE);
    int x2 = (int)(r[3] * SCALE);
    int y2 = (int)(r[4] * SCALE);
    x1 = min(max(x1, 0), FW - 1);
    y1 = min(max(y1, 0), FH - 1);
    x2 = min(max(x2, 0), FW - 1);
    y2 = min(max(y2, 0), FH - 1);
    int hh = y2 - y1 + 1, ww = x2 - x1 + 1;

    int ys = y1 + (p * hh) / 7, ye = y1 + ((p + 1) * hh + 6) / 7;
    int xs = x1 + (q * ww) / 7, xe = x1 + ((q + 1) * ww + 6) / 7;

    const float* base = feat + ((size_t)b * CCH + c) * HW;
    float m = NEGF;
    for (int y = ys; y < ye; ++y)
        for (int x = xs; x < xe; ++x)
            m = fmaxf(m, base[y * FW + x]);
    out[idx] = m;
}

extern "C" void kernel_launch(void* const* d_in, const int* in_sizes, int n_in,
                              void* d_out, int out_size, void* d_ws, size_t ws_size,
                              hipStream_t stream) {
    const float* feat = (const float*)d_in[0];
    const float* rois = (const float*)d_in[1];
    float* out = (float*)d_out;

    const size_t need = FEATT_BYTES + (NROIS + 8) * sizeof(int);
    if (ws_size < need) {
        const int total = NROIS * CCH * 49;
        roipool_fallback<<<(total + 255) / 256, 256, 0, stream>>>(feat, rois, out);
        return;
    }

    float* featT = (float*)d_ws;
    int*   perm  = (int*)((char*)d_ws + FEATT_BYTES);
    int*   cntG  = perm + NROIS;
    int*   offG  = cntG + 4;

    dim3 tg(HW / 4, 4);                      // (361, 4)
    transpose_bucket_kernel<<<tg, 256, 0, stream>>>(feat, rois, featT,
                                                    perm, cntG, offG);

    roipool_kernel<<<4096, 256, 0, stream>>>(featT, rois, perm, cntG, offG, out);
}